// Round 13
// baseline (69.742 us; speedup 1.0000x reference)
//
#include <hip/hip_runtime.h>
#include <math.h>

// Workspace layout (floats):
//   [256,800)        S     : atomic-fallback accumulators S[b][q]
//   [800,832)        n     : atomic-fallback squared norms
//   [1024,35840)     Spart : partials [b][q][chunk]  32*17*64
//   [35840,37888)    npart : norm partials [b][chunk] 32*64
#define WS_S     256
#define WS_N     800
#define WS_PART  1024
#define WS_NPART 35840
#define WS_NEED_BYTES ((WS_NPART + 2048) * 4)

typedef _Float16 half8 __attribute__((ext_vector_type(8)));
typedef float f32x4 __attribute__((ext_vector_type(4)));

__device__ inline float2 cmul2(float2 a, float2 b) {
  return make_float2(a.x * b.x - a.y * b.y, a.x * b.y + a.y * b.x);
}

__device__ inline int ringperm(int x) {
  if ((x >> 3) & 1) x ^= 4;
  if ((x >> 2) & 1) x ^= 2;
  if ((x >> 1) & 1) x ^= 1;
  if (x & 1)        x ^= 8;
  return x;
}

// yzy element from precomputed half-angle sin/cos tables (LDS)
__device__ inline float2 yzy_elem_tab(const float* scs, const float* ccs,
                                      int layer, int r, int c) {
  float2 prod = make_float2(1.f, 0.f);
#pragma unroll
  for (int k = 0; k < 4; k++) {
    int base = layer * 12 + 3 * k;
    float s0 = scs[base + 0], c0 = ccs[base + 0];
    float s1 = scs[base + 1], c1 = ccs[base + 1];
    float s2 = scs[base + 2], c2 = ccs[base + 2];
    float A = c2 * c0, B = s2 * s0, C = c2 * s0, D = s2 * c0;
    float2 m00 = make_float2( c1 * (A - B), -s1 * (A + B));
    float2 m01 = make_float2(-c1 * (C + D),  s1 * (C - D));
    float2 m10 = make_float2( c1 * (C + D),  s1 * (C - D));
    float2 m11 = make_float2( c1 * (A - B),  s1 * (A + B));
    int rb = (r >> (3 - k)) & 1, cb = (c >> (3 - k)) & 1;
    float2 mm = rb ? (cb ? m11 : m10) : (cb ? m01 : m00);
    prod = cmul2(prod, mm);
  }
  return prod;
}

// XOR-fold swizzle on 16B-block index
__device__ inline int swzB(int B) {
  int h = B >> 3;
  int f = (h ^ (h >> 3) ^ (h >> 6)) & 7;
  return B ^ f;
}

// Gram-window via MFMA, FOUR accumulator chains of depth 2 (round-7 core).
// LDS: 2048 16B blocks of 8 f16, block index swizzled. i-field at pos bits [P,P+4).
template <int P>
__device__ inline float windowM(const half8* __restrict__ HB, const float* __restrict__ Tr) {
  const int t = threadIdx.x;
  const int w = t >> 6, l = t & 63, g = (l >> 4) & 3, i = l & 15;
  f32x4 hh[4] = {{0.f, 0.f, 0.f, 0.f}, {0.f, 0.f, 0.f, 0.f},
                 {0.f, 0.f, 0.f, 0.f}, {0.f, 0.f, 0.f, 0.f}};
#pragma unroll
  for (int s = 0; s < 2; s++) {
#pragma unroll
    for (int c = 0; c < 4; c++) {
      int rest = (w << 5) | ((s * 4 + c) << 2) | g;  // 7-bit rest
      int rl = rest & ((1 << (P - 3)) - 1), rh = rest >> (P - 3);
      int pos = (rl << 3) | (i << P) | (rh << (P + 4));
      half8 fr = HB[swzB(pos >> 3)];
      hh[c] = __builtin_amdgcn_mfma_f32_16x16x32_f16(fr, fr, hh[c], 0, 0, 0);
    }
  }
  float part = 0.f;
#pragma unroll
  for (int reg = 0; reg < 4; reg++)
    part = fmaf(Tr[reg], (hh[0][reg] + hh[1][reg]) + (hh[2][reg] + hh[3][reg]), part);
  return part;
}

__global__ void init_zero_kernel(float* __restrict__ ws) {
  int t = threadIdx.x;
  for (int k = t; k < 576; k += 256) ws[WS_S + k] = 0.f;
}

// Per-block in-LDS T build (replaces the serial build_T kernel): 36 sincos
// total per block (one thread each), then the 256-thread complex pipeline in
// HB-aliased scratch. All blocks compute the identical T.
// modes (mode = bid&1): 0 = contiguous chunk (reg-P3 + LDS p=4..10 + rot image
// p=0..2 + norms); 2 = strided row tile (p=11..16, L3-resident).
__global__ __launch_bounds__(256, 4) void passAll_kernel(const float* __restrict__ vb,
                                                         const float* __restrict__ wgt,
                                                         float* ws, int use_part) {
  __shared__ half8 HB[2048];   // exactly 32 KB; T-scratch and reduce alias it
  const int t = threadIdx.x;
  const int bid = blockIdx.x;

  const int mode = (bid & 1) ? 2 : 0;
  const int idx = bid >> 1;
  const int b = idx >> 6, chunk = idx & 63;
  const int l = t & 63, g = (l >> 4) & 3, i = l & 15;

  // ---- in-block T build (HB used as scratch; done before staging) ----
  float* base = (float*)HB;
  float2* Ub = (float2*)base;            // [256] 2 KB
  float2* Yb = (float2*)(base + 512);    // [256] 2 KB
  float2* Wb = (float2*)(base + 1024);   // [256] 2 KB
  float* scs = base + 1536;              // [36]
  float* ccs = base + 1572;              // [36]
  float* Tsh = base + 1792;              // [256] 1 KB

  if (t < 36) {
    float s, c;
    sincosf(0.5f * wgt[t], &s, &c);
    scs[t] = s; ccs[t] = c;
  }
  __syncthreads();
  {
    const int r = t >> 4, c = t & 15;
    Ub[t] = yzy_elem_tab(scs, ccs, 0, r, c);
    __syncthreads();
    Wb[ringperm(r) * 16 + c] = Ub[t];
    __syncthreads(); Ub[t] = Wb[t]; __syncthreads();
    Yb[t] = yzy_elem_tab(scs, ccs, 1, r, c);
    __syncthreads();
    {
      float2 s = make_float2(0.f, 0.f);
#pragma unroll
      for (int k = 0; k < 16; k++) {
        float2 pr = cmul2(Yb[r * 16 + k], Ub[k * 16 + c]);
        s.x += pr.x; s.y += pr.y;
      }
      Wb[t] = s;
    }
    __syncthreads(); Ub[t] = Wb[t]; __syncthreads();
    Wb[ringperm(r) * 16 + c] = Ub[t];
    __syncthreads(); Ub[t] = Wb[t]; __syncthreads();
    Yb[t] = yzy_elem_tab(scs, ccs, 2, r, c);
    __syncthreads();
    {
      float2 s = make_float2(0.f, 0.f);
#pragma unroll
      for (int k = 0; k < 16; k++) {
        float2 pr = cmul2(Yb[r * 16 + k], Ub[k * 16 + c]);
        s.x += pr.x; s.y += pr.y;
      }
      Wb[t] = s;
    }
    __syncthreads(); Ub[t] = Wb[t]; __syncthreads();
    Yb[t] = Ub[(r ^ 15) * 16 + c];   // M = X^{x4}: row r <- row r^15
    __syncthreads();
    float s_re = 0.f;
#pragma unroll
    for (int k = 0; k < 16; k++) {
      float2 u = Ub[k * 16 + r], m = Yb[k * 16 + c];
      s_re += u.x * m.x + u.y * m.y;
    }
    Tsh[t] = s_re;  // T[r][c]
  }
  __syncthreads();

  // per-thread T values: T[g*4+reg][i] is all this lane ever needs
  float Treg[4];
#pragma unroll
  for (int reg = 0; reg < 4; reg++) Treg[reg] = Tsh[((g * 4 + reg) << 4) + i];
  __syncthreads();  // Treg extracted; HB free for staging

  float part[11];
#pragma unroll
  for (int k = 0; k < 11; k++) part[k] = 0.f;

  float nsum = 0.f;
  if (mode == 0) {
    const float4* src4 = ((const float4*)vb) + ((size_t)b << 18) + ((size_t)chunk << 12);
    half8 h[8];  // staged fragments, consumed by register-resident P=3 below
#pragma unroll
    for (int j = 0; j < 8; j++) {
      int B = j * 256 + t;
      float4 aa = src4[2 * B], cc = src4[2 * B + 1];
      nsum = fmaf(aa.x, aa.x, nsum); nsum = fmaf(aa.y, aa.y, nsum);
      nsum = fmaf(aa.z, aa.z, nsum); nsum = fmaf(aa.w, aa.w, nsum);
      nsum = fmaf(cc.x, cc.x, nsum); nsum = fmaf(cc.y, cc.y, nsum);
      nsum = fmaf(cc.z, cc.z, nsum); nsum = fmaf(cc.w, cc.w, nsum);
      half8 hh;
      hh[0] = (_Float16)aa.x; hh[1] = (_Float16)aa.y; hh[2] = (_Float16)aa.z; hh[3] = (_Float16)aa.w;
      hh[4] = (_Float16)cc.x; hh[5] = (_Float16)cc.y; hh[6] = (_Float16)cc.z; hh[7] = (_Float16)cc.w;
      h[j] = hh;
      HB[swzB(B)] = hh;
    }
    // window P=3 (q=13) straight from registers; runs under the barrier wait
    {
      f32x4 hh[4] = {{0.f, 0.f, 0.f, 0.f}, {0.f, 0.f, 0.f, 0.f},
                     {0.f, 0.f, 0.f, 0.f}, {0.f, 0.f, 0.f, 0.f}};
#pragma unroll
      for (int j = 0; j < 8; j++)
        hh[j & 3] = __builtin_amdgcn_mfma_f32_16x16x32_f16(h[j], h[j], hh[j & 3], 0, 0, 0);
      float p0 = 0.f;
#pragma unroll
      for (int reg = 0; reg < 4; reg++)
        p0 = fmaf(Treg[reg], (hh[0][reg] + hh[1][reg]) + (hh[2][reg] + hh[3][reg]), p0);
      part[0] = p0;
    }
  } else {
    // tile: 32 consecutive floats x 512 rows at stride 2048 floats
    const float4* src4 = ((const float4*)vb) + ((size_t)b << 18) + chunk * 8;
#pragma unroll
    for (int j = 0; j < 8; j++) {
      int B = j * 256 + t;
      int row = B >> 2;
      int c4 = (B & 3) * 2;
      float4 aa = src4[row * 512 + c4], cc = src4[row * 512 + c4 + 1];
      half8 hh;
      hh[0] = (_Float16)aa.x; hh[1] = (_Float16)aa.y; hh[2] = (_Float16)aa.z; hh[3] = (_Float16)aa.w;
      hh[4] = (_Float16)cc.x; hh[5] = (_Float16)cc.y; hh[6] = (_Float16)cc.z; hh[7] = (_Float16)cc.w;
      HB[swzB(B)] = hh;
    }
  }
  __syncthreads();

  if (mode == 0) {
    // image0 LDS windows: p = P, q = 16 - p  -> win 1..7 <-> q 12..6
    part[1] += windowM<4>(HB, Treg);
    part[2] += windowM<5>(HB, Treg);
    part[3] += windowM<6>(HB, Treg);
    part[4] += windowM<7>(HB, Treg);
    part[5] += windowM<8>(HB, Treg);
    part[6] += windowM<9>(HB, Treg);
    part[7] += windowM<10>(HB, Treg);
    // re-read staged blocks, in-place transpose -> image1 (rot+3)
    half8 h2[8];
#pragma unroll
    for (int j = 0; j < 8; j++) h2[j] = HB[swzB(j * 256 + t)];
    __syncthreads();  // all image0 reads complete before overwrite
#pragma unroll
    for (int e = 0; e < 8; e++) {
      half8 v;
#pragma unroll
      for (int j = 0; j < 8; j++) v[j] = h2[j][e];
      HB[swzB(8 * t + e)] = v;
    }
    __syncthreads();
    // image1: p = P - 3 in {0,1,2} -> win 8,9,10 <-> q 16,15,14
    part[8]  += windowM<3>(HB, Treg);
    part[9]  += windowM<4>(HB, Treg);
    part[10] += windowM<5>(HB, Treg);
  } else {
    // p = P + 6 in {11..16} -> win 0..5 <-> q 5..0
    part[0] += windowM<5>(HB, Treg);
    part[1] += windowM<6>(HB, Treg);
    part[2] += windowM<7>(HB, Treg);
    part[3] += windowM<8>(HB, Treg);
    part[4] += windowM<9>(HB, Treg);
    part[5] += windowM<10>(HB, Treg);
  }
  __syncthreads();  // all reads of HB done; safe to alias reduce scratch

  float* red2 = (float*)HB;  // 12*256 floats = 12 KB
#pragma unroll
  for (int k = 0; k < 11; k++) red2[k * 256 + t] = part[k];
  red2[11 * 256 + t] = nsum;
  __syncthreads();

  // batched cross-block reduction: 16-thread group per value (12 live groups)
  const int win = t >> 4, idx16 = t & 15;
  const float4* r4 = (const float4*)red2;
  float4 q0 = r4[win * 64 + idx16],      q1 = r4[win * 64 + 16 + idx16];
  float4 q2 = r4[win * 64 + 32 + idx16], q3 = r4[win * 64 + 48 + idx16];
  float s1 = ((q0.x + q0.y) + (q0.z + q0.w)) + ((q1.x + q1.y) + (q1.z + q1.w)) +
             ((q2.x + q2.y) + (q2.z + q2.w)) + ((q3.x + q3.y) + (q3.z + q3.w));
#pragma unroll
  for (int off = 8; off; off >>= 1) s1 += __shfl_down(s1, off, 16);

  if (idx16 == 0) {
    if (mode == 0) {
      if (win < 11) {
        int q = (win < 8) ? (13 - win) : (24 - win);
        if (use_part) ws[WS_PART + (b * 17 + q) * 64 + chunk] = s1;
        else          atomicAdd(ws + WS_S + b * 17 + q, s1);
      } else if (win == 11) {
        if (use_part) ws[WS_NPART + b * 64 + chunk] = s1;
        else          atomicAdd(ws + WS_N + b, s1);
      }
    } else {
      if (win < 6) {
        int q = 5 - win;
        if (use_part) ws[WS_PART + (b * 17 + q) * 64 + chunk] = s1;
        else          atomicAdd(ws + WS_S + b * 17 + q, s1);
      }
    }
  }
}

__global__ void finalize_kernel(const float* __restrict__ ws, float* __restrict__ out,
                                int use_part) {
  int i = blockIdx.x * 256 + threadIdx.x;
  if (i < 544) {
    int b = i / 17;
    float s, n;
    if (use_part) {
      const float* sp = ws + WS_PART + i * 64;
      s = 0.f;
#pragma unroll 8
      for (int c = 0; c < 64; c++) s += sp[c];
      const float* np = ws + WS_NPART + b * 64;
      n = 0.f;
#pragma unroll 8
      for (int c = 0; c < 64; c++) n += np[c];
    } else {
      s = ws[WS_S + i];
      n = ws[WS_N + b];
    }
    out[i] = s / fmaxf(n, 1e-24f);
  }
}

extern "C" void kernel_launch(void* const* d_in, const int* in_sizes, int n_in,
                              void* d_out, int out_size, void* d_ws, size_t ws_size,
                              hipStream_t stream) {
  const float* vb  = (const float*)d_in[0];
  const float* wgt = (const float*)d_in[1];
  float* out = (float*)d_out;
  float* ws  = (float*)d_ws;
  int use_part = (ws_size >= (size_t)WS_NEED_BYTES) ? 1 : 0;

  if (!use_part) init_zero_kernel<<<1, 256, 0, stream>>>(ws);
  passAll_kernel<<<4096, 256, 0, stream>>>(vb, wgt, ws, use_part);
  finalize_kernel<<<3, 256, 0, stream>>>(ws, out, use_part);
}

// Round 14
// 59.383 us; speedup vs baseline: 1.1744x; 1.1744x over previous
//
#include <hip/hip_runtime.h>
#include <math.h>

// Workspace layout (floats):
//   [0,256)          T     : full symmetric Re(U^H M U)
//   [256,800)        S     : atomic-fallback accumulators S[b][q]
//   [800,832)        n     : atomic-fallback squared norms
//   [1024,35840)     Spart : partials [b][q][chunk]  32*17*64
//   [35840,37888)    npart : norm partials [b][chunk] 32*64
#define WS_TU    0
#define WS_S     256
#define WS_N     800
#define WS_PART  1024
#define WS_NPART 35840
#define WS_NEED_BYTES ((WS_NPART + 2048) * 4)

typedef _Float16 half8 __attribute__((ext_vector_type(8)));
typedef float f32x4 __attribute__((ext_vector_type(4)));

__device__ inline float2 cmul2(float2 a, float2 b) {
  return make_float2(a.x * b.x - a.y * b.y, a.x * b.y + a.y * b.x);
}

__device__ inline int ringperm(int x) {
  if ((x >> 3) & 1) x ^= 4;
  if ((x >> 2) & 1) x ^= 2;
  if ((x >> 1) & 1) x ^= 1;
  if (x & 1)        x ^= 8;
  return x;
}

__device__ inline float2 yzy_elem(const float* wgt, int layer, int r, int c) {
  float2 prod = make_float2(1.f, 0.f);
#pragma unroll
  for (int k = 0; k < 4; k++) {
    float t0 = wgt[layer * 12 + 3 * k + 0];
    float t1 = wgt[layer * 12 + 3 * k + 1];
    float t2 = wgt[layer * 12 + 3 * k + 2];
    float s0, c0, s1, c1, s2, c2;
    sincosf(0.5f * t0, &s0, &c0);
    sincosf(0.5f * t1, &s1, &c1);
    sincosf(0.5f * t2, &s2, &c2);
    float A = c2 * c0, B = s2 * s0, C = c2 * s0, D = s2 * c0;
    float2 m00 = make_float2( c1 * (A - B), -s1 * (A + B));
    float2 m01 = make_float2(-c1 * (C + D),  s1 * (C - D));
    float2 m10 = make_float2( c1 * (C + D),  s1 * (C - D));
    float2 m11 = make_float2( c1 * (A - B),  s1 * (A + B));
    int rb = (r >> (3 - k)) & 1, cb = (c >> (3 - k)) & 1;
    float2 mm = rb ? (cb ? m11 : m10) : (cb ? m01 : m00);
    prod = cmul2(prod, mm);
  }
  return prod;
}

__global__ void build_T_kernel(const float* __restrict__ wgt, float* __restrict__ ws) {
  __shared__ float2 U[256], Y[256], W[256];
  const int t = threadIdx.x;
  const int r = t >> 4, c = t & 15;

  // zero the atomic-fallback accumulators (no separate memset dispatch)
  for (int k = t; k < 576; k += 256) ws[WS_S + k] = 0.f;

  U[t] = yzy_elem(wgt, 0, r, c);
  __syncthreads();
  W[ringperm(r) * 16 + c] = U[t];
  __syncthreads(); U[t] = W[t]; __syncthreads();
  Y[t] = yzy_elem(wgt, 1, r, c);
  __syncthreads();
  {
    float2 s = make_float2(0.f, 0.f);
#pragma unroll
    for (int k = 0; k < 16; k++) {
      float2 pr = cmul2(Y[r * 16 + k], U[k * 16 + c]);
      s.x += pr.x; s.y += pr.y;
    }
    W[t] = s;
  }
  __syncthreads(); U[t] = W[t]; __syncthreads();
  W[ringperm(r) * 16 + c] = U[t];
  __syncthreads(); U[t] = W[t]; __syncthreads();
  Y[t] = yzy_elem(wgt, 2, r, c);
  __syncthreads();
  {
    float2 s = make_float2(0.f, 0.f);
#pragma unroll
    for (int k = 0; k < 16; k++) {
      float2 pr = cmul2(Y[r * 16 + k], U[k * 16 + c]);
      s.x += pr.x; s.y += pr.y;
    }
    W[t] = s;
  }
  __syncthreads(); U[t] = W[t]; __syncthreads();
  Y[t] = U[(r ^ 15) * 16 + c];
  __syncthreads();
  float s_re = 0.f;
#pragma unroll
  for (int k = 0; k < 16; k++) {
    float2 u = U[k * 16 + r], m = Y[k * 16 + c];
    s_re += u.x * m.x + u.y * m.y;
  }
  ws[WS_TU + t] = s_re;  // full symmetric T
}

// XOR-fold swizzle on 16B-block index
__device__ inline int swzB(int B) {
  int h = B >> 3;
  int f = (h ^ (h >> 3) ^ (h >> 6)) & 7;
  return B ^ f;
}

// Gram-window via MFMA, FOUR accumulator chains of depth 2 (round-7 core).
// LDS: 2048 16B blocks of 8 f16, block index swizzled. i-field at pos bits [P,P+4).
template <int P>
__device__ inline float windowM(const half8* __restrict__ HB, const float* __restrict__ Tr) {
  const int t = threadIdx.x;
  const int w = t >> 6, l = t & 63, g = (l >> 4) & 3, i = l & 15;
  f32x4 hh[4] = {{0.f, 0.f, 0.f, 0.f}, {0.f, 0.f, 0.f, 0.f},
                 {0.f, 0.f, 0.f, 0.f}, {0.f, 0.f, 0.f, 0.f}};
#pragma unroll
  for (int s = 0; s < 2; s++) {
#pragma unroll
    for (int c = 0; c < 4; c++) {
      int rest = (w << 5) | ((s * 4 + c) << 2) | g;  // 7-bit rest
      int rl = rest & ((1 << (P - 3)) - 1), rh = rest >> (P - 3);
      int pos = (rl << 3) | (i << P) | (rh << (P + 4));
      half8 fr = HB[swzB(pos >> 3)];
      hh[c] = __builtin_amdgcn_mfma_f32_16x16x32_f16(fr, fr, hh[c], 0, 0, 0);
    }
  }
  float part = 0.f;
#pragma unroll
  for (int reg = 0; reg < 4; reg++)
    part = fmaf(Tr[reg], (hh[0][reg] + hh[1][reg]) + (hh[2][reg] + hh[3][reg]), part);
  return part;
}

// modes: 0 = contiguous chunk: register-resident P=3 window (staging fragments
//            are valid P=3 MFMA fragments); norm comes FREE from that Gram's
//            trace (diag lane g==i>>2, reg==i&3). LDS windows p=4..10, then
//            register transpose (h[] kept live) -> image1 (rot+3, p=0..2).
//        2 = strided row tile (p=11..16), grid tail (L3-warm).
__global__ __launch_bounds__(256, 4) void passAll_kernel(const float* __restrict__ vb,
                                                         float* ws, int use_part) {
  __shared__ half8 HB[2048];   // exactly 32 KB; reduce scratch aliases it later
  const int t = threadIdx.x;
  const int bid = blockIdx.x;

  const int mode = (bid < 2048) ? 0 : 2;
  const int idx = (bid < 2048) ? bid : bid - 2048;
  const int b = idx >> 6, chunk = idx & 63;
  const int l = t & 63, g = (l >> 4) & 3, i = l & 15;

  float part[11];
#pragma unroll
  for (int k = 0; k < 11; k++) part[k] = 0.f;

  float Treg[4];
  float nsum = 0.f;
  half8 h[8];  // mode 0: staged fragments, kept live through image0 windows
  if (mode == 0) {
    const float4* src4 = ((const float4*)vb) + ((size_t)b << 18) + ((size_t)chunk << 12);
#pragma unroll
    for (int j = 0; j < 8; j++) {
      int B = j * 256 + t;
      float4 aa = src4[2 * B], cc = src4[2 * B + 1];
      half8 hh;
      hh[0] = (_Float16)aa.x; hh[1] = (_Float16)aa.y; hh[2] = (_Float16)aa.z; hh[3] = (_Float16)aa.w;
      hh[4] = (_Float16)cc.x; hh[5] = (_Float16)cc.y; hh[6] = (_Float16)cc.z; hh[7] = (_Float16)cc.w;
      h[j] = hh;
      HB[swzB(B)] = hh;
    }
#pragma unroll
    for (int reg = 0; reg < 4; reg++) Treg[reg] = ws[WS_TU + ((g * 4 + reg) << 4) + i];
    // window P=3 (q=13) straight from registers; runs under the barrier wait.
    // Its Gram diagonal also yields the chunk's squared norm (trace).
    {
      f32x4 hh[4] = {{0.f, 0.f, 0.f, 0.f}, {0.f, 0.f, 0.f, 0.f},
                     {0.f, 0.f, 0.f, 0.f}, {0.f, 0.f, 0.f, 0.f}};
#pragma unroll
      for (int j = 0; j < 8; j++)
        hh[j & 3] = __builtin_amdgcn_mfma_f32_16x16x32_f16(h[j], h[j], hh[j & 3], 0, 0, 0);
      float p0 = 0.f;
#pragma unroll
      for (int reg = 0; reg < 4; reg++) {
        float hm = (hh[0][reg] + hh[1][reg]) + (hh[2][reg] + hh[3][reg]);
        p0 = fmaf(Treg[reg], hm, p0);
        if (g == (i >> 2) && reg == (i & 3)) nsum = hm;  // G[r][r], r = i
      }
      part[0] = p0;
    }
  } else {
    // tile: 32 consecutive floats x 512 rows at stride 2048 floats
    const float4* src4 = ((const float4*)vb) + ((size_t)b << 18) + chunk * 8;
#pragma unroll
    for (int j = 0; j < 8; j++) {
      int B = j * 256 + t;
      int row = B >> 2;
      int c4 = (B & 3) * 2;
      float4 aa = src4[row * 512 + c4], cc = src4[row * 512 + c4 + 1];
      half8 hh;
      hh[0] = (_Float16)aa.x; hh[1] = (_Float16)aa.y; hh[2] = (_Float16)aa.z; hh[3] = (_Float16)aa.w;
      hh[4] = (_Float16)cc.x; hh[5] = (_Float16)cc.y; hh[6] = (_Float16)cc.z; hh[7] = (_Float16)cc.w;
      HB[swzB(B)] = hh;
    }
#pragma unroll
    for (int reg = 0; reg < 4; reg++) Treg[reg] = ws[WS_TU + ((g * 4 + reg) << 4) + i];
  }
  __syncthreads();

  if (mode == 0) {
    // image0 LDS windows: p = P, q = 16 - p  -> win 1..7 <-> q 12..6
    part[1] += windowM<4>(HB, Treg);
    part[2] += windowM<5>(HB, Treg);
    part[3] += windowM<6>(HB, Treg);
    part[4] += windowM<7>(HB, Treg);
    part[5] += windowM<8>(HB, Treg);
    part[6] += windowM<9>(HB, Treg);
    part[7] += windowM<10>(HB, Treg);
    __syncthreads();  // all image0 reads complete before overwrite
    // in-place transpose from the live staging registers -> image1 (rot+3):
    // element x[2048u + c] -> pos = c*8 + u; thread t holds h[j][e] = x[2048j+8t+e]
#pragma unroll
    for (int e = 0; e < 8; e++) {
      half8 v;
#pragma unroll
      for (int j = 0; j < 8; j++) v[j] = h[j][e];
      HB[swzB(8 * t + e)] = v;
    }
    __syncthreads();
    // image1: p = P - 3 in {0,1,2} -> win 8,9,10 <-> q 16,15,14
    part[8]  += windowM<3>(HB, Treg);
    part[9]  += windowM<4>(HB, Treg);
    part[10] += windowM<5>(HB, Treg);
  } else {
    // p = P + 6 in {11..16} -> win 0..5 <-> q 5..0
    part[0] += windowM<5>(HB, Treg);
    part[1] += windowM<6>(HB, Treg);
    part[2] += windowM<7>(HB, Treg);
    part[3] += windowM<8>(HB, Treg);
    part[4] += windowM<9>(HB, Treg);
    part[5] += windowM<10>(HB, Treg);
  }
  __syncthreads();  // all reads of HB done; safe to alias reduce scratch

  float* red2 = (float*)HB;  // 12*256 floats = 12 KB
#pragma unroll
  for (int k = 0; k < 11; k++) red2[k * 256 + t] = part[k];
  red2[11 * 256 + t] = nsum;
  __syncthreads();

  // batched cross-block reduction: 16-thread group per value (12 live groups)
  const int win = t >> 4, idx16 = t & 15;
  const float4* r4 = (const float4*)red2;
  float4 q0 = r4[win * 64 + idx16],      q1 = r4[win * 64 + 16 + idx16];
  float4 q2 = r4[win * 64 + 32 + idx16], q3 = r4[win * 64 + 48 + idx16];
  float s1 = ((q0.x + q0.y) + (q0.z + q0.w)) + ((q1.x + q1.y) + (q1.z + q1.w)) +
             ((q2.x + q2.y) + (q2.z + q2.w)) + ((q3.x + q3.y) + (q3.z + q3.w));
#pragma unroll
  for (int off = 8; off; off >>= 1) s1 += __shfl_down(s1, off, 16);

  if (idx16 == 0) {
    if (mode == 0) {
      if (win < 11) {
        int q = (win < 8) ? (13 - win) : (24 - win);
        if (use_part) ws[WS_PART + (b * 17 + q) * 64 + chunk] = s1;
        else          atomicAdd(ws + WS_S + b * 17 + q, s1);
      } else if (win == 11) {
        if (use_part) ws[WS_NPART + b * 64 + chunk] = s1;
        else          atomicAdd(ws + WS_N + b, s1);
      }
    } else {
      if (win < 6) {
        int q = 5 - win;
        if (use_part) ws[WS_PART + (b * 17 + q) * 64 + chunk] = s1;
        else          atomicAdd(ws + WS_S + b * 17 + q, s1);
      }
    }
  }
}

__global__ void finalize_kernel(const float* __restrict__ ws, float* __restrict__ out,
                                int use_part) {
  int i = blockIdx.x * 256 + threadIdx.x;
  if (i < 544) {
    int b = i / 17;
    float s, n;
    if (use_part) {
      const float* sp = ws + WS_PART + i * 64;
      s = 0.f;
#pragma unroll 8
      for (int c = 0; c < 64; c++) s += sp[c];
      const float* np = ws + WS_NPART + b * 64;
      n = 0.f;
#pragma unroll 8
      for (int c = 0; c < 64; c++) n += np[c];
    } else {
      s = ws[WS_S + i];
      n = ws[WS_N + b];
    }
    out[i] = s / fmaxf(n, 1e-24f);
  }
}

extern "C" void kernel_launch(void* const* d_in, const int* in_sizes, int n_in,
                              void* d_out, int out_size, void* d_ws, size_t ws_size,
                              hipStream_t stream) {
  const float* vb  = (const float*)d_in[0];
  const float* wgt = (const float*)d_in[1];
  float* out = (float*)d_out;
  float* ws  = (float*)d_ws;
  int use_part = (ws_size >= (size_t)WS_NEED_BYTES) ? 1 : 0;

  build_T_kernel<<<1, 256, 0, stream>>>(wgt, ws);
  passAll_kernel<<<4096, 256, 0, stream>>>(vb, ws, use_part);
  finalize_kernel<<<3, 256, 0, stream>>>(ws, out, use_part);
}